// Round 1
// baseline (201.056 us; speedup 1.0000x reference)
//
#include <hip/hip_runtime.h>

// Tall-skinny GEMM: out[65536,64] = x[65536,512] @ W[512,64], fp32 in/out.
// bf16 MFMA 16x16x32. W prepped once per launch into MFMA B-fragment layout
// in d_ws (64 KiB) by prep_w.
//
// R4: drop the LDS B-stage entirely. d_ws is L2-resident (64 KiB, every XCD
// caches it), so each wave reads its B fragments straight from global with a
// 1-kt-ahead register double-buffer (4 x dwordx4 = 1 KiB coalesced per wave
// per kt). This removes the 64 KiB LDS footprint (was capping us at 2
// blocks/CU = 16 waves/CU), the full-block staging phase, and the
// __syncthreads() vmcnt(0)-drain barrier. 256-thread blocks, grid=1024,
// launch_bounds(256,5) -> ~20 waves/CU, no barriers anywhere.
// A-prefetch ring is 3 deep; loop fully unrolled so all ring/buffer indices
// are compile-time (no scratch).

#define KDIM  512
#define NDIM  64

typedef __attribute__((ext_vector_type(8))) short short8;   // 8 bf16 = 4 VGPRs
typedef __attribute__((ext_vector_type(4))) float f32x4;    // MFMA accumulator

__device__ __forceinline__ unsigned short f2bf(float f) {
    // round-to-nearest-even fp32 -> bf16
    unsigned int u = __float_as_uint(f);
    u += 0x7FFFu + ((u >> 16) & 1u);
    return (unsigned short)(u >> 16);
}

// ---------------------------------------------------------------------------
// Prep: W[512,64] fp32 -> bf16 B-fragments in d_ws.
// Slot s = (kt*4 + nt)*64 + lane holds 8 bf16:
//   B[kt*32 + 8*(lane>>4) + j][nt*16 + (lane&15)],  j in [0,8)
// 4096 slots * 16B = 64KB.  (unchanged from R3 — layout proven correct)
// ---------------------------------------------------------------------------
__global__ void prep_w(const float* __restrict__ W, uint4* __restrict__ ws) {
    int t = blockIdx.x * 256 + threadIdx.x;   // 0..4095
    int l = t & 63;
    int ntkt = t >> 6;
    int nt = ntkt & 3, kt = ntkt >> 2;
    int n = nt * 16 + (l & 15);
    int kbase = kt * 32 + (l >> 4) * 8;
    unsigned int p[4];
#pragma unroll
    for (int jj = 0; jj < 4; ++jj) {
        unsigned int lo = f2bf(W[(kbase + 2 * jj    ) * NDIM + n]);
        unsigned int hi = f2bf(W[(kbase + 2 * jj + 1) * NDIM + n]);
        p[jj] = lo | (hi << 16);
    }
    uint4 v; v.x = p[0]; v.y = p[1]; v.z = p[2]; v.w = p[3];
    ws[t] = v;
}

// ---------------------------------------------------------------------------
// Main: 256 thr = 4 waves; wave handles 16 rows; block 64 rows; grid = 1024.
// No LDS, no barriers. B fragments double-buffered from L2.
// ---------------------------------------------------------------------------
__global__ __launch_bounds__(256, 5) void gemm_tall(
    const float* __restrict__ x, const short8* __restrict__ wsB,
    float* __restrict__ out)
{
    const int tid  = threadIdx.x;
    const int wave = tid >> 6;
    const int lane = tid & 63;
    const int c = lane & 15;          // A row within wave stripe / C col
    const int q = lane >> 4;          // k-quad
    const int rowBase = blockIdx.x * 64 + wave * 16;
    const float* xr = x + (size_t)(rowBase + c) * KDIM + q * 8;

    // A-prefetch ring, 3 deep. Slot s holds data for kt%3==s;
    // k = kt*32 + q*8 + j, j in [0,8).
    float4 A0[3], A1[3];
#pragma unroll
    for (int i = 0; i < 3; ++i) {
        A0[i] = *(const float4*)(xr + i * 32);
        A1[i] = *(const float4*)(xr + i * 32 + 4);
    }

    // B double buffer: bc = current kt, bn = next kt (L2-hot loads).
    short8 bc[4], bn[4];
#pragma unroll
    for (int nt = 0; nt < 4; ++nt) bc[nt] = wsB[nt * 64 + lane];

    f32x4 acc[4] = {{0.f,0.f,0.f,0.f},{0.f,0.f,0.f,0.f},
                    {0.f,0.f,0.f,0.f},{0.f,0.f,0.f,0.f}};

#pragma unroll
    for (int kt = 0; kt < 16; ++kt) {
        const int s = kt % 3;                 // compile-time (full unroll)
        float4 p0 = A0[s], p1 = A1[s];
        if (kt < 13) {                        // refill ring 3 kt ahead
            A0[s] = *(const float4*)(xr + (kt + 3) * 32);
            A1[s] = *(const float4*)(xr + (kt + 3) * 32 + 4);
        }
        if (kt < 15) {                        // prefetch next kt's B frags
#pragma unroll
            for (int nt = 0; nt < 4; ++nt)
                bn[nt] = wsB[((kt + 1) * 4 + nt) * 64 + lane];
        }
        short8 af;
        af[0] = (short)f2bf(p0.x); af[1] = (short)f2bf(p0.y);
        af[2] = (short)f2bf(p0.z); af[3] = (short)f2bf(p0.w);
        af[4] = (short)f2bf(p1.x); af[5] = (short)f2bf(p1.y);
        af[6] = (short)f2bf(p1.z); af[7] = (short)f2bf(p1.w);
#pragma unroll
        for (int nt = 0; nt < 4; ++nt)
            acc[nt] = __builtin_amdgcn_mfma_f32_16x16x32_bf16(af, bc[nt], acc[nt], 0, 0, 0);
#pragma unroll
        for (int nt = 0; nt < 4; ++nt) bc[nt] = bn[nt];   // renamed, not copied
    }

    // C/D layout: col = lane&15, row = 4*(lane>>4) + i   [m89/m91 verified]
#pragma unroll
    for (int nt = 0; nt < 4; ++nt) {
#pragma unroll
        for (int i = 0; i < 4; ++i) {
            out[(size_t)(rowBase + q * 4 + i) * NDIM + nt * 16 + c] = acc[nt][i];
        }
    }
}

// ---------------------------------------------------------------------------
// Fallback (ws too small — not expected on this harness): plain fp32 dot.
// Correctness-only path.
// ---------------------------------------------------------------------------
__global__ void gemm_fallback(const float* __restrict__ x,
                              const float* __restrict__ W,
                              float* __restrict__ out)
{
    int idx = blockIdx.x * 256 + threadIdx.x;   // over 65536*64 outputs
    int b = idx >> 6;
    int o = idx & 63;
    const float* xb = x + (size_t)b * KDIM;
    float s = 0.f;
    for (int k = 0; k < KDIM; ++k) s = fmaf(xb[k], W[k * NDIM + o], s);
    out[idx] = s;
}

extern "C" void kernel_launch(void* const* d_in, const int* in_sizes, int n_in,
                              void* d_out, int out_size, void* d_ws, size_t ws_size,
                              hipStream_t stream) {
    const float* x = (const float*)d_in[0];
    const float* W = (const float*)d_in[1];
    float* out = (float*)d_out;

    if (ws_size >= 65536) {
        prep_w<<<16, 256, 0, stream>>>(W, (uint4*)d_ws);
        gemm_tall<<<1024, 256, 0, stream>>>(x, (const short8*)d_ws, out);
    } else {
        gemm_fallback<<<16384, 256, 0, stream>>>(x, W, out);
    }
}

// Round 2
// 198.264 us; speedup vs baseline: 1.0141x; 1.0141x over previous
//
#include <hip/hip_runtime.h>

// Tall-skinny GEMM: out[65536,64] = x[65536,512] @ W[512,64], fp32 in/out.
// bf16 MFMA 16x16x32. W prepped once per launch into MFMA B-fragment layout
// in d_ws (64 KiB) by prep_w.
//
// R5: R3 structure (512 thr / 128 rows / 64 KB LDS B / grid 512 = exactly
// 2 blocks/CU resident) but the B-stage now uses async
// __builtin_amdgcn_global_load_lds width=16 (8 per thread, linear layout —
// dest is wave-uniform base + lane*16, which our slot order satisfies).
// This removes the global->VGPR->LDS round-trip and all staging VALU; the
// A-prefetch ring is issued BEFORE the stage so a single vmcnt(0) drain at
// the barrier covers both. B reads in the K-loop come from LDS (~low lgkm
// latency, compiler fine-schedules) instead of R4's 1-kt-ahead L2 chain.

#define KDIM  512
#define NDIM  64

typedef __attribute__((ext_vector_type(8))) short short8;   // 8 bf16 = 4 VGPRs
typedef __attribute__((ext_vector_type(4))) float f32x4;    // MFMA accumulator

__device__ __forceinline__ unsigned short f2bf(float f) {
    // round-to-nearest-even fp32 -> bf16
    unsigned int u = __float_as_uint(f);
    u += 0x7FFFu + ((u >> 16) & 1u);
    return (unsigned short)(u >> 16);
}

// ---------------------------------------------------------------------------
// Prep: W[512,64] fp32 -> bf16 B-fragments in d_ws.
// Slot s = (kt*4 + nt)*64 + lane holds 8 bf16:
//   B[kt*32 + 8*(lane>>4) + j][nt*16 + (lane&15)],  j in [0,8)
// 4096 slots * 16B = 64KB.  (layout proven correct R3/R4)
// ---------------------------------------------------------------------------
__global__ void prep_w(const float* __restrict__ W, uint4* __restrict__ ws) {
    int t = blockIdx.x * 256 + threadIdx.x;   // 0..4095
    int l = t & 63;
    int ntkt = t >> 6;
    int nt = ntkt & 3, kt = ntkt >> 2;
    int n = nt * 16 + (l & 15);
    int kbase = kt * 32 + (l >> 4) * 8;
    unsigned int p[4];
#pragma unroll
    for (int jj = 0; jj < 4; ++jj) {
        unsigned int lo = f2bf(W[(kbase + 2 * jj    ) * NDIM + n]);
        unsigned int hi = f2bf(W[(kbase + 2 * jj + 1) * NDIM + n]);
        p[jj] = lo | (hi << 16);
    }
    uint4 v; v.x = p[0]; v.y = p[1]; v.z = p[2]; v.w = p[3];
    ws[t] = v;
}

// ---------------------------------------------------------------------------
// Main: 512 thr = 8 waves; block handles 128 rows, wave 16 rows. grid = 512
// (2 blocks/CU, whole grid co-resident). B staged to LDS asynchronously.
// ---------------------------------------------------------------------------
__global__ __launch_bounds__(512, 4) void gemm_tall(
    const float* __restrict__ x, const uint4* __restrict__ wsB,
    float* __restrict__ out)
{
    __shared__ __align__(16) uint4 Bl4[4096];   // 64KB bf16 B-fragments

    const int tid  = threadIdx.x;
    const int wave = tid >> 6;
    const int lane = tid & 63;
    const int c = lane & 15;          // A row within wave stripe / C col
    const int q = lane >> 4;          // k-quad
    const int rowBase = blockIdx.x * 128 + wave * 16;
    const float* xr = x + (size_t)(rowBase + c) * KDIM + q * 8;

    // A-prefetch ring, 4 deep, issued FIRST: its HBM latency hides under the
    // async B staging + barrier drain. Slot s holds data for kt%4==s;
    // k = kt*32 + q*8 + j, j in [0,8).
    float4 A0[4], A1[4];
#pragma unroll
    for (int i = 0; i < 4; ++i) {
        A0[i] = *(const float4*)(xr + i * 32);
        A1[i] = *(const float4*)(xr + i * 32 + 4);
    }

    // Async B stage: 8 x 16B per thread, dest linear in lane (slot tid+i*512
    // => LDS byte addr = wave-uniform base + lane*16 — the required layout).
#pragma unroll
    for (int i = 0; i < 8; ++i) {
        __builtin_amdgcn_global_load_lds(
            (const __attribute__((address_space(1))) void*)(wsB + tid + i * 512),
            (__attribute__((address_space(3))) void*)(&Bl4[tid + i * 512]),
            16, 0, 0);
    }
    __syncthreads();   // drains vmcnt(0): staging AND the A-ring complete

    const short8* Bf = (const short8*)Bl4;

    f32x4 acc[4] = {{0.f,0.f,0.f,0.f},{0.f,0.f,0.f,0.f},
                    {0.f,0.f,0.f,0.f},{0.f,0.f,0.f,0.f}};

#pragma unroll
    for (int kt = 0; kt < 16; ++kt) {
        const int s = kt & 3;
        float4 p0 = A0[s], p1 = A1[s];
        if (kt < 12) {                      // refill ring 4 kt ahead
            A0[s] = *(const float4*)(xr + (kt + 4) * 32);
            A1[s] = *(const float4*)(xr + (kt + 4) * 32 + 4);
        }
        short8 af;
        af[0] = (short)f2bf(p0.x); af[1] = (short)f2bf(p0.y);
        af[2] = (short)f2bf(p0.z); af[3] = (short)f2bf(p0.w);
        af[4] = (short)f2bf(p1.x); af[5] = (short)f2bf(p1.y);
        af[6] = (short)f2bf(p1.z); af[7] = (short)f2bf(p1.w);
#pragma unroll
        for (int nt = 0; nt < 4; ++nt) {
            short8 bf = Bf[(kt * 4 + nt) * 64 + lane];
            acc[nt] = __builtin_amdgcn_mfma_f32_16x16x32_bf16(af, bf, acc[nt], 0, 0, 0);
        }
    }

    // C/D layout: col = lane&15, row = 4*(lane>>4) + i   [m89/m91 verified]
#pragma unroll
    for (int nt = 0; nt < 4; ++nt) {
#pragma unroll
        for (int i = 0; i < 4; ++i) {
            out[(size_t)(rowBase + q * 4 + i) * NDIM + nt * 16 + c] = acc[nt][i];
        }
    }
}

// ---------------------------------------------------------------------------
// Fallback (ws too small — not expected on this harness): plain fp32 dot.
// Correctness-only path.
// ---------------------------------------------------------------------------
__global__ void gemm_fallback(const float* __restrict__ x,
                              const float* __restrict__ W,
                              float* __restrict__ out)
{
    int idx = blockIdx.x * 256 + threadIdx.x;   // over 65536*64 outputs
    int b = idx >> 6;
    int o = idx & 63;
    const float* xb = x + (size_t)b * KDIM;
    float s = 0.f;
    for (int k = 0; k < KDIM; ++k) s = fmaf(xb[k], W[k * NDIM + o], s);
    out[idx] = s;
}

extern "C" void kernel_launch(void* const* d_in, const int* in_sizes, int n_in,
                              void* d_out, int out_size, void* d_ws, size_t ws_size,
                              hipStream_t stream) {
    const float* x = (const float*)d_in[0];
    const float* W = (const float*)d_in[1];
    float* out = (float*)d_out;

    if (ws_size >= 65536) {
        prep_w<<<16, 256, 0, stream>>>(W, (uint4*)d_ws);
        gemm_tall<<<512, 512, 0, stream>>>(x, (const uint4*)d_ws, out);
    } else {
        gemm_fallback<<<16384, 256, 0, stream>>>(x, W, out);
    }
}